// Round 1
// baseline (1546.805 us; speedup 1.0000x reference)
//
#include <hip/hip_runtime.h>
#include <hip/hip_bf16.h>

#define DM 48      // D_MODEL
#define NS 21      // num slots
#define HDm 24     // head dim
#define ITERS 3
#define WST 52     // weight row stride (floats) - padded for LDS banks
#define KST 104    // K/V row stride (floats): [K 0..47 | V 48..95 | pad]
#define NWAVE 4

__device__ __forceinline__ float dot4(const float4 a, const float4 b) {
    return (a.x*b.x + a.y*b.y) + (a.z*b.z + a.w*b.w);
}

__global__ __launch_bounds__(256, 1) void fusion_kernel(
    const float* __restrict__ slot, const float* __restrict__ fq,
    const float* __restrict__ ipw,  const float* __restrict__ ipb,
    const float* __restrict__ opw,  const float* __restrict__ opb,
    const float* __restrict__ lnqg, const float* __restrict__ lnqb,
    const float* __restrict__ lnkg, const float* __restrict__ lnkb,
    const float* __restrict__ wih,  const float* __restrict__ whh,
    const float* __restrict__ bih,  const float* __restrict__ bhh,
    const float* __restrict__ sigr, const float* __restrict__ praw,
    const float* __restrict__ p1w,  const float* __restrict__ p1b,
    const float* __restrict__ p2w,  const float* __restrict__ p2b,
    float* __restrict__ outp, const int M)
{
    // ---- weights (block-shared, loaded once) ----
    __shared__ __align__(16) float s_wkv[96*WST];   // rows 0-47: wk, 48-95: wv
    __shared__ __align__(16) float s_wq [48*WST];
    __shared__ __align__(16) float s_opw[48*WST];
    __shared__ __align__(16) float s_wih[144*WST];
    __shared__ __align__(16) float s_whh[144*WST];
    __shared__ __align__(16) __hip_bfloat16 s_p1[48*WST];
    __shared__ __align__(16) __hip_bfloat16 s_p2[48*WST];
    __shared__ float s_bq[48], s_bk[48], s_bv[48], s_ob[48];
    __shared__ float s_bih[144], s_bhh[144];
    __shared__ float s_lnqg[48], s_lnqb[48], s_lnkg[48], s_lnkb[48];
    __shared__ float s_sig[48], s_p1b[48], s_p2b[48], s_fq[48];
    __shared__ float s_pp;
    // ---- per-wave scratch ----
    __shared__ __align__(16) float s_row[NWAVE][NS*KST];  // kvn, then K|V
    __shared__ __align__(16) float s_q  [NWAVE][64];
    __shared__ __align__(16) float s_x  [NWAVE][64];
    __shared__ __align__(16) float s_Q  [NWAVE][64];
    __shared__ __align__(16) float s_aw [NWAVE][64];
    __shared__ __align__(16) float s_o  [NWAVE][64];

    const int tid = threadIdx.x;
    for (int i = tid; i < 48*48; i += 256) {
        int r = i / 48, c = i - r*48;
        s_wq [r*WST+c] = ipw[i];
        s_opw[r*WST+c] = opw[i];
        s_p1 [r*WST+c] = __float2bfloat16(p1w[i]);
        s_p2 [r*WST+c] = __float2bfloat16(p2w[i]);
    }
    for (int i = tid; i < 96*48; i += 256) {
        int r = i / 48, c = i - r*48;
        s_wkv[r*WST+c] = ipw[48*48 + i];     // wk rows 48-95, wv rows 96-143
    }
    for (int i = tid; i < 144*48; i += 256) {
        int r = i / 48, c = i - r*48;
        s_wih[r*WST+c] = wih[i];
        s_whh[r*WST+c] = whh[i];
    }
    if (tid < 48) {
        s_bq[tid] = ipb[tid]; s_bk[tid] = ipb[48+tid]; s_bv[tid] = ipb[96+tid];
        s_ob[tid] = opb[tid];
        s_lnqg[tid] = lnqg[tid]; s_lnqb[tid] = lnqb[tid];
        s_lnkg[tid] = lnkg[tid]; s_lnkb[tid] = lnkb[tid];
        s_sig[tid] = log1pf(__expf(sigr[tid])) + 0.01f;  // softplus + 0.01
        s_p1b[tid] = p1b[tid]; s_p2b[tid] = p2b[tid];
        s_fq[tid]  = fq[tid];
    }
    if (tid < 144) { s_bih[tid] = bih[tid]; s_bhh[tid] = bhh[tid]; }
    if (tid == 0) s_pp = 1.5f + log1pf(__expf(praw[0]));
    __syncthreads();

    const int w = tid >> 6, l = tid & 63;
    const int jl = (l < DM) ? l : 0;          // clamped lane->row index
    float* __restrict__ row = s_row[w];
    float* __restrict__ vq  = s_q[w];
    float* __restrict__ vx  = s_x[w];
    float* __restrict__ vQ  = s_Q[w];
    float* __restrict__ vaw = s_aw[w];
    float* __restrict__ vo  = s_o[w];
    const float pexp = s_pp;
    const float pinv = 1.0f / pexp;
    const int g = l >> 4, u = l & 15;         // 16-lane group layout for LN(kv)
    const int gw0 = blockIdx.x * NWAVE + w;
    const int stride = gridDim.x * NWAVE;

    for (int m = gw0; m < M; m += stride) {
        const float* __restrict__ kvp = slot + (size_t)m * (NS*DM);

        // ---- LN(kv) -> row[n*KST + 0..47]  (hoisted: kv const across iters) ----
        #pragma unroll
        for (int i = 0; i < 6; ++i) {
            int n = i*4 + g;
            bool act = (n < NS);
            int nc = act ? n : 0;
            float x0 = kvp[nc*DM + u];
            float x1 = kvp[nc*DM + 16 + u];
            float x2 = kvp[nc*DM + 32 + u];
            float s1 = x0 + x1 + x2;
            float s2 = x0*x0 + x1*x1 + x2*x2;
            #pragma unroll
            for (int off = 8; off; off >>= 1) {   // reduce within 16-lane group
                s1 += __shfl_xor(s1, off);
                s2 += __shfl_xor(s2, off);
            }
            float mu = s1 * (1.f/48.f);
            float var = s2 * (1.f/48.f) - mu*mu;
            float rs = rsqrtf(var + 1e-5f);
            if (act) {
                row[nc*KST + u]      = (x0 - mu)*rs*s_lnkg[u]    + s_lnkb[u];
                row[nc*KST + 16 + u] = (x1 - mu)*rs*s_lnkg[16+u] + s_lnkb[16+u];
                row[nc*KST + 32 + u] = (x2 - mu)*rs*s_lnkg[32+u] + s_lnkb[32+u];
            }
        }

        // ---- K,V = kvn @ {wk,wv}^T + b   (hoisted; lane = output col) ----
        float accK[NS], accV[NS];
        #pragma unroll
        for (int n = 0; n < NS; ++n) { accK[n] = s_bk[jl]; accV[n] = s_bv[jl]; }
        #pragma unroll 2
        for (int d4 = 0; d4 < 12; ++d4) {
            float4 wk4 = *(const float4*)&s_wkv[jl*WST + d4*4];
            float4 wv4 = *(const float4*)&s_wkv[(48+jl)*WST + d4*4];
            #pragma unroll
            for (int n = 0; n < NS; ++n) {
                float4 x4 = *(const float4*)&row[n*KST + d4*4];  // broadcast
                accK[n] += dot4(wk4, x4);
                accV[n] += dot4(wv4, x4);
            }
        }
        // overwrite kvn region with K|V (all reads above precede; per-wave DS in-order)
        if (l < DM) {
            #pragma unroll
            for (int n = 0; n < NS; ++n) {
                row[n*KST + l]      = accK[n];
                row[n*KST + 48 + l] = accV[n];
            }
        }

        // ---- 3 GRU-attention iterations ----
        float qreg = s_fq[jl];
        if (l < DM) vq[l] = qreg;
        #pragma unroll 1
        for (int it = 0; it < ITERS; ++it) {
            // LN(q)
            float xq = (l < DM) ? qreg : 0.f;
            float s1 = xq, s2 = xq*xq;
            #pragma unroll
            for (int off = 32; off; off >>= 1) {
                s1 += __shfl_xor(s1, off);
                s2 += __shfl_xor(s2, off);
            }
            float mu = s1*(1.f/48.f);
            float rs = rsqrtf(s2*(1.f/48.f) - mu*mu + 1e-5f);
            if (l < DM) vx[l] = (xq - mu)*rs*s_lnqg[jl] + s_lnqb[jl];
            // Q = qn @ wq^T + bq
            float4 a4 = {0,0,0,0};
            #pragma unroll
            for (int d4 = 0; d4 < 12; ++d4) {
                float4 w4 = *(const float4*)&s_wq[jl*WST + d4*4];
                float4 x4 = *(const float4*)&vx[d4*4];
                a4.x += w4.x*x4.x; a4.y += w4.y*x4.y; a4.z += w4.z*x4.z; a4.w += w4.w*x4.w;
            }
            if (l < DM) vQ[l] = s_bq[jl] + (a4.x + a4.y) + (a4.z + a4.w);
            // scores[h][n] (lanes 0..41), softmax over n
            int ls = (l < 42) ? l : 0;
            int h = (ls >= 21) ? 1 : 0;
            int sn = ls - h*21;
            float4 b4 = {0,0,0,0};
            #pragma unroll
            for (int d4 = 0; d4 < 6; ++d4) {
                float4 q4 = *(const float4*)&vQ[h*HDm + d4*4];
                float4 k4 = *(const float4*)&row[sn*KST + h*HDm + d4*4];
                b4.x += q4.x*k4.x; b4.y += q4.y*k4.y; b4.z += q4.z*k4.z; b4.w += q4.w*k4.w;
            }
            float sc = ((b4.x+b4.y)+(b4.z+b4.w)) * 0.2041241452319315f; // 1/sqrt(24)
            if (l < 42) vaw[l] = sc;
            float mx = -3.4e38f;
            #pragma unroll
            for (int k = 0; k < NS; ++k) mx = fmaxf(mx, vaw[h*21 + k]);
            float ex = __expf(sc - mx);
            if (l < 42) vaw[l] = ex;
            float se = 0.f;
            #pragma unroll
            for (int k = 0; k < NS; ++k) se += vaw[h*21 + k];
            float aw = ex / se;
            if (l < 42) vaw[l] = aw;
            // attn[h*24+dd] = sum_n aw[h][n] * V[n][h*24+dd]
            int h2 = (jl >= HDm) ? 1 : 0;
            float at = 0.f;
            #pragma unroll
            for (int n = 0; n < NS; ++n)
                at += vaw[h2*21 + n] * row[n*KST + 48 + jl];
            if (l < DM) vx[l] = at;
            // out = attn @ opw^T + ob
            float4 c4 = {0,0,0,0};
            #pragma unroll
            for (int d4 = 0; d4 < 12; ++d4) {
                float4 w4 = *(const float4*)&s_opw[jl*WST + d4*4];
                float4 x4 = *(const float4*)&vx[d4*4];
                c4.x += w4.x*x4.x; c4.y += w4.y*x4.y; c4.z += w4.z*x4.z; c4.w += w4.w*x4.w;
            }
            if (l < DM) vo[l] = s_ob[jl] + (c4.x + c4.y) + (c4.z + c4.w);
            // GRUCell(out, q): lane owns channel jl; 6 independent dot chains
            float gr = s_bih[jl], gz = s_bih[48+jl], gn = s_bih[96+jl];
            float hr = s_bhh[jl], hz = s_bhh[48+jl], hn = s_bhh[96+jl];
            #pragma unroll
            for (int d4 = 0; d4 < 12; ++d4) {
                float4 o4 = *(const float4*)&vo[d4*4];
                float4 q4 = *(const float4*)&vq[d4*4];
                gr += dot4(*(const float4*)&s_wih[jl*WST + d4*4], o4);
                gz += dot4(*(const float4*)&s_wih[(48+jl)*WST + d4*4], o4);
                gn += dot4(*(const float4*)&s_wih[(96+jl)*WST + d4*4], o4);
                hr += dot4(*(const float4*)&s_whh[jl*WST + d4*4], q4);
                hz += dot4(*(const float4*)&s_whh[(48+jl)*WST + d4*4], q4);
                hn += dot4(*(const float4*)&s_whh[(96+jl)*WST + d4*4], q4);
            }
            float r = 1.f / (1.f + __expf(-(gr + hr)));
            float z = 1.f / (1.f + __expf(-(gz + hz)));
            float nn = tanhf(gn + r*hn);
            qreg = (1.f - z)*nn + z*qreg;
            if (l < DM) vq[l] = qreg;
        }

        // ---- outputs ----
        if (l < NS)
            outp[(size_t)M*DM + (size_t)m*NS + l] = 0.5f*(vaw[l] + vaw[21 + l]);
        // yield activation
        float f = qreg;
        float ratio = fminf(fabsf(f) / s_sig[jl], 15.f);
        float rp = __powf(ratio, pexp);
        f = f / __powf(1.f + rp, pinv);
        if (l < DM) vx[l] = f;
        // proj1 (bf16 weights) + ReLU
        float4 a4 = {0,0,0,0};
        #pragma unroll
        for (int d4 = 0; d4 < 12; ++d4) {
            uint2 rw = *(const uint2*)&s_p1[jl*WST + d4*4];
            float4 x4 = *(const float4*)&vx[d4*4];
            a4.x += __uint_as_float(rw.x << 16)          * x4.x;
            a4.y += __uint_as_float(rw.x & 0xffff0000u)  * x4.y;
            a4.z += __uint_as_float(rw.y << 16)          * x4.z;
            a4.w += __uint_as_float(rw.y & 0xffff0000u)  * x4.w;
        }
        float h1 = fmaxf(0.f, s_p1b[jl] + (a4.x + a4.y) + (a4.z + a4.w));
        if (l < DM) vx[l] = h1;
        // proj2
        float4 c4 = {0,0,0,0};
        #pragma unroll
        for (int d4 = 0; d4 < 12; ++d4) {
            uint2 rw = *(const uint2*)&s_p2[jl*WST + d4*4];
            float4 x4 = *(const float4*)&vx[d4*4];
            c4.x += __uint_as_float(rw.x << 16)          * x4.x;
            c4.y += __uint_as_float(rw.x & 0xffff0000u)  * x4.y;
            c4.z += __uint_as_float(rw.y << 16)          * x4.z;
            c4.w += __uint_as_float(rw.y & 0xffff0000u)  * x4.w;
        }
        if (l < DM) outp[(size_t)m*DM + l] = s_p2b[jl] + (c4.x + c4.y) + (c4.z + c4.w);
    }
}

extern "C" void kernel_launch(void* const* d_in, const int* in_sizes, int n_in,
                              void* d_out, int out_size, void* d_ws, size_t ws_size,
                              hipStream_t stream) {
    const float* slot = (const float*)d_in[0];
    const float* fq   = (const float*)d_in[1];
    const float* ipw  = (const float*)d_in[2];
    const float* ipb  = (const float*)d_in[3];
    const float* opw  = (const float*)d_in[4];
    const float* opb  = (const float*)d_in[5];
    const float* lnqg = (const float*)d_in[6];
    const float* lnqb = (const float*)d_in[7];
    const float* lnkg = (const float*)d_in[8];
    const float* lnkb = (const float*)d_in[9];
    const float* wih  = (const float*)d_in[10];
    const float* whh  = (const float*)d_in[11];
    const float* bihp = (const float*)d_in[12];
    const float* bhhp = (const float*)d_in[13];
    const float* sigr = (const float*)d_in[14];
    const float* praw = (const float*)d_in[15];
    const float* p1w  = (const float*)d_in[16];
    const float* p1b  = (const float*)d_in[17];
    const float* p2w  = (const float*)d_in[18];
    const float* p2b  = (const float*)d_in[19];
    const int M = in_sizes[0] / (NS*DM);   // 65536
    fusion_kernel<<<dim3(256), dim3(256), 0, stream>>>(
        slot, fq, ipw, ipb, opw, opb, lnqg, lnqb, lnkg, lnkb,
        wih, whh, bihp, bhhp, sigr, praw, p1w, p1b, p2w, p2b,
        (float*)d_out, M);
}

// Round 2
// 785.161 us; speedup vs baseline: 1.9700x; 1.9700x over previous
//
#include <hip/hip_runtime.h>
#include <hip/hip_bf16.h>

#define DM 48      // D_MODEL
#define NS 21      // num slots
#define HDm 24     // head dim
#define ITERS 3
#define WST 52     // fp32 LDS row stride (floats; 208B, 16B-aligned)
#define BST 56     // bf16 LDS row stride (elems; 112B, 16B-aligned)
#define PST 52     // p1/p2 bf16 stride (104B, 8B-aligned rows for b64 reads)
#define VST 49     // V bf16 row stride
#define NWAVE 12   // 768 threads

__device__ __forceinline__ unsigned short f2bu(float f) {
    __hip_bfloat16 h = __float2bfloat16(f);
    return *reinterpret_cast<unsigned short*>(&h);
}
__device__ __forceinline__ float bu2f_lo(unsigned u) { return __uint_as_float(u << 16); }
__device__ __forceinline__ float bu2f_hi(unsigned u) { return __uint_as_float(u & 0xffff0000u); }

// 8 fmas: bf16x8 weights (uint4) * two float4 x-vectors -> acc
#define FMA8(acc, u, xa, xb)                                              \
    acc = fmaf(bu2f_lo((u).x), (xa).x, acc);                              \
    acc = fmaf(bu2f_hi((u).x), (xa).y, acc);                              \
    acc = fmaf(bu2f_lo((u).y), (xa).z, acc);                              \
    acc = fmaf(bu2f_hi((u).y), (xa).w, acc);                              \
    acc = fmaf(bu2f_lo((u).z), (xb).x, acc);                              \
    acc = fmaf(bu2f_hi((u).z), (xb).y, acc);                              \
    acc = fmaf(bu2f_lo((u).w), (xb).z, acc);                              \
    acc = fmaf(bu2f_hi((u).w), (xb).w, acc);

__global__ __launch_bounds__(768, 3) void fusion_kernel(
    const float* __restrict__ slot, const float* __restrict__ fq,
    const float* __restrict__ ipw,  const float* __restrict__ ipb,
    const float* __restrict__ opw,  const float* __restrict__ opb,
    const float* __restrict__ lnqg, const float* __restrict__ lnqb,
    const float* __restrict__ lnkg, const float* __restrict__ lnkb,
    const float* __restrict__ wih,  const float* __restrict__ whh,
    const float* __restrict__ bih,  const float* __restrict__ bhh,
    const float* __restrict__ sigr, const float* __restrict__ praw,
    const float* __restrict__ p1w,  const float* __restrict__ p1b,
    const float* __restrict__ p2w,  const float* __restrict__ p2b,
    float* __restrict__ outp, const int M)
{
    // ---- block-shared weights (loaded once) ----
    __shared__ __align__(16) float s_wq [48*WST];            //  9,984 B
    __shared__ __align__(16) float s_opw[48*WST];            //  9,984 B
    __shared__ __align__(16) unsigned short s_wkv[96*BST];   // 10,752 B (wk|wv)
    __shared__ __align__(16) unsigned short s_wih[144*BST];  // 16,128 B
    __shared__ __align__(16) unsigned short s_whh[144*BST];  // 16,128 B
    __shared__ __align__(16) unsigned short s_p1[48*PST];    //  4,992 B
    __shared__ __align__(16) unsigned short s_p2[48*PST];    //  4,992 B
    __shared__ float s_bq[48], s_bk[48], s_bv[48], s_ob[48];
    __shared__ float s_bih[144], s_bhh[144];
    __shared__ float s_lnqg[48], s_lnqb[48], s_lnkg[48], s_lnkb[48];
    __shared__ float s_sig[48], s_p1b[48], s_p2b[48], s_fq[48];
    __shared__ float s_pp;
    // ---- per-wave scratch ----
    __shared__ __align__(16) float s_row[NWAVE][NS*WST];     // kvn then K: 52,416 B
    __shared__ __align__(16) unsigned short s_V[NWAVE][NS*VST]; // V bf16: 24,696 B
    __shared__ __align__(16) float s_vec[NWAVE][192];        // q | x/attn/o | Q/aw : 9,216 B

    const int tid = threadIdx.x;
    for (int i = tid; i < 48*48; i += 768) {
        int r = i / 48, c = i - r*48;
        s_wq [r*WST+c] = ipw[i];
        s_opw[r*WST+c] = opw[i];
        s_p1 [r*PST+c] = f2bu(p1w[i]);
        s_p2 [r*PST+c] = f2bu(p2w[i]);
    }
    for (int i = tid; i < 96*48; i += 768) {
        int r = i / 48, c = i - r*48;
        s_wkv[r*BST+c] = f2bu(ipw[48*48 + i]);   // rows 0-47: wk, 48-95: wv
    }
    for (int i = tid; i < 144*48; i += 768) {
        int r = i / 48, c = i - r*48;
        s_wih[r*BST+c] = f2bu(wih[i]);
        s_whh[r*BST+c] = f2bu(whh[i]);
    }
    if (tid < 48) {
        s_bq[tid] = ipb[tid]; s_bk[tid] = ipb[48+tid]; s_bv[tid] = ipb[96+tid];
        s_ob[tid] = opb[tid];
        s_lnqg[tid] = lnqg[tid]; s_lnqb[tid] = lnqb[tid];
        s_lnkg[tid] = lnkg[tid]; s_lnkb[tid] = lnkb[tid];
        s_sig[tid] = log1pf(__expf(sigr[tid])) + 0.01f;
        s_p1b[tid] = p1b[tid]; s_p2b[tid] = p2b[tid];
        s_fq[tid]  = fq[tid];
    }
    if (tid < 144) { s_bih[tid] = bih[tid]; s_bhh[tid] = bhh[tid]; }
    if (tid == 0) s_pp = 1.5f + log1pf(__expf(praw[0]));
    __syncthreads();

    const int w = tid >> 6, l = tid & 63;
    const int jl = (l < DM) ? l : 0;
    float* __restrict__ row = s_row[w];
    unsigned short* __restrict__ vV = s_V[w];
    float* __restrict__ vq  = s_vec[w];
    float* __restrict__ vx  = s_vec[w] + 64;   // x / attn / o (in-order aliasing)
    float* __restrict__ vQw = s_vec[w] + 128;  // Q then aw
    const float pexp = s_pp;
    const float pinv = 1.0f / pexp;
    const int g = l >> 4, u = l & 15;          // 16-lane groups for LN(kv)
    const int h2 = (jl >= HDm) ? 1 : 0;
    const int sh = l >> 5, snn = l & 31;       // softmax lanes: (head, slot)
    const bool sact = snn < NS;
    const int sn = sact ? snn : 0;

    for (int m = blockIdx.x*NWAVE + w; m < M; m += gridDim.x*NWAVE) {
        const float* __restrict__ kvp = slot + (size_t)m * (NS*DM);

        // ---- LN(kv): hoisted (kv constant across iterations) ----
        #pragma unroll
        for (int i = 0; i < 6; ++i) {
            int n = i*4 + g;
            bool act = (n < NS);
            int nc = act ? n : 0;
            float x0 = kvp[nc*DM + u];
            float x1 = kvp[nc*DM + 16 + u];
            float x2 = kvp[nc*DM + 32 + u];
            float s1 = x0 + x1 + x2;
            float s2 = x0*x0 + x1*x1 + x2*x2;
            #pragma unroll
            for (int off = 8; off; off >>= 1) {
                s1 += __shfl_xor(s1, off);
                s2 += __shfl_xor(s2, off);
            }
            float mu = s1 * (1.f/48.f);
            float var = s2 * (1.f/48.f) - mu*mu;
            float rs = rsqrtf(var + 1e-5f);
            if (act) {
                row[nc*WST + u]      = (x0 - mu)*rs*s_lnkg[u]    + s_lnkb[u];
                row[nc*WST + 16 + u] = (x1 - mu)*rs*s_lnkg[16+u] + s_lnkb[16+u];
                row[nc*WST + 32 + u] = (x2 - mu)*rs*s_lnkg[32+u] + s_lnkb[32+u];
            }
        }

        // ---- K,V projection (hoisted). lane = out channel; 42 indep fma chains ----
        float accK[NS], accV[NS];
        #pragma unroll
        for (int n = 0; n < NS; ++n) { accK[n] = s_bk[jl]; accV[n] = s_bv[jl]; }
        #pragma unroll 2
        for (int d8 = 0; d8 < 6; ++d8) {
            uint4 kw = *(const uint4*)&s_wkv[jl*BST + d8*8];
            uint4 vw = *(const uint4*)&s_wkv[(48+jl)*BST + d8*8];
            #pragma unroll
            for (int n = 0; n < NS; ++n) {
                const float* xp = &row[n*WST + d8*8];
                float4 xa = *(const float4*)xp;
                float4 xb = *(const float4*)(xp + 4);
                FMA8(accK[n], kw, xa, xb);
                FMA8(accV[n], vw, xa, xb);
            }
        }
        // overwrite kvn with K (all reads above precede; per-wave DS in-order); V->bf16
        if (l < DM) {
            #pragma unroll
            for (int n = 0; n < NS; ++n) {
                row[n*WST + l] = accK[n];
                vV[n*VST + l]  = f2bu(accV[n]);
            }
        }

        // ---- 3 GRU-attention iterations ----
        float qreg = s_fq[jl];
        if (l < DM) vq[l] = qreg;
        #pragma unroll 1
        for (int it = 0; it < ITERS; ++it) {
            // LN(q)
            float xq = (l < DM) ? qreg : 0.f;
            float s1 = xq, s2 = xq*xq;
            #pragma unroll
            for (int off = 32; off; off >>= 1) {
                s1 += __shfl_xor(s1, off);
                s2 += __shfl_xor(s2, off);
            }
            float mu = s1*(1.f/48.f);
            float rs = rsqrtf(s2*(1.f/48.f) - mu*mu + 1e-5f);
            if (l < DM) vx[l] = (xq - mu)*rs*s_lnqg[jl] + s_lnqb[jl];
            // Q = qn @ wq^T + bq
            float4 a4 = {0,0,0,0};
            #pragma unroll
            for (int d4 = 0; d4 < 12; ++d4) {
                float4 w4 = *(const float4*)&s_wq[jl*WST + d4*4];
                float4 x4 = *(const float4*)&vx[d4*4];
                a4.x = fmaf(w4.x, x4.x, a4.x); a4.y = fmaf(w4.y, x4.y, a4.y);
                a4.z = fmaf(w4.z, x4.z, a4.z); a4.w = fmaf(w4.w, x4.w, a4.w);
            }
            if (l < DM) vQw[l] = s_bq[jl] + (a4.x + a4.y) + (a4.z + a4.w);
            // scores: lane = (h=l>>5, n=l&31); shuffle softmax within 32-lane group
            float4 b4 = {0,0,0,0};
            #pragma unroll
            for (int d4 = 0; d4 < 6; ++d4) {
                float4 q4 = *(const float4*)&vQw[sh*HDm + d4*4];
                float4 k4 = *(const float4*)&row[sn*WST + sh*HDm + d4*4];
                b4.x = fmaf(q4.x, k4.x, b4.x); b4.y = fmaf(q4.y, k4.y, b4.y);
                b4.z = fmaf(q4.z, k4.z, b4.z); b4.w = fmaf(q4.w, k4.w, b4.w);
            }
            float sc = sact ? ((b4.x+b4.y)+(b4.z+b4.w)) * 0.20412414523193154f
                            : -3.0e38f;
            float mx = sc;
            #pragma unroll
            for (int off = 16; off; off >>= 1) mx = fmaxf(mx, __shfl_xor(mx, off));
            float ex = __expf(sc - mx);
            float se = ex;
            #pragma unroll
            for (int off = 16; off; off >>= 1) se += __shfl_xor(se, off);
            float aw = ex / se;
            vQw[l] = aw;                       // aw overlay (after all Q reads)
            // attn[jl] = sum_n aw[h][n] * V[n][jl]  (V bf16, aw broadcast)
            float at = 0.f;
            #pragma unroll
            for (int n = 0; n < NS; ++n)
                at = fmaf(vQw[h2*32 + n],
                          __uint_as_float(((unsigned)vV[n*VST + jl]) << 16), at);
            if (l < DM) vx[l] = at;
            // out = attn @ opw^T + ob   (writes vx after all reads: safe alias)
            float4 c4 = {0,0,0,0};
            #pragma unroll
            for (int d4 = 0; d4 < 12; ++d4) {
                float4 w4 = *(const float4*)&s_opw[jl*WST + d4*4];
                float4 x4 = *(const float4*)&vx[d4*4];
                c4.x = fmaf(w4.x, x4.x, c4.x); c4.y = fmaf(w4.y, x4.y, c4.y);
                c4.z = fmaf(w4.z, x4.z, c4.z); c4.w = fmaf(w4.w, x4.w, c4.w);
            }
            if (l < DM) vx[l] = s_ob[jl] + (c4.x + c4.y) + (c4.z + c4.w);
            // GRUCell(out=vx, q=vq): 6 independent bf16-weight dot chains
            float gr = s_bih[jl], gz = s_bih[48+jl], gn = s_bih[96+jl];
            float hr = s_bhh[jl], hz = s_bhh[48+jl], hn = s_bhh[96+jl];
            #pragma unroll 2
            for (int d8 = 0; d8 < 6; ++d8) {
                float4 oa = *(const float4*)&vx[d8*8];
                float4 ob4 = *(const float4*)&vx[d8*8 + 4];
                float4 qa = *(const float4*)&vq[d8*8];
                float4 qb = *(const float4*)&vq[d8*8 + 4];
                uint4 u0 = *(const uint4*)&s_wih[jl*BST + d8*8];
                uint4 u1 = *(const uint4*)&s_wih[(48+jl)*BST + d8*8];
                uint4 u2 = *(const uint4*)&s_wih[(96+jl)*BST + d8*8];
                uint4 u3 = *(const uint4*)&s_whh[jl*BST + d8*8];
                uint4 u4 = *(const uint4*)&s_whh[(48+jl)*BST + d8*8];
                uint4 u5 = *(const uint4*)&s_whh[(96+jl)*BST + d8*8];
                FMA8(gr, u0, oa, ob4);
                FMA8(gz, u1, oa, ob4);
                FMA8(gn, u2, oa, ob4);
                FMA8(hr, u3, qa, qb);
                FMA8(hz, u4, qa, qb);
                FMA8(hn, u5, qa, qb);
            }
            float r = 1.f / (1.f + __expf(-(gr + hr)));
            float z = 1.f / (1.f + __expf(-(gz + hz)));
            float nn = tanhf(gn + r*hn);
            qreg = (1.f - z)*nn + z*qreg;
            if (l < DM) vq[l] = qreg;
        }

        // ---- outputs ----
        if (l < NS)
            outp[(size_t)M*DM + (size_t)m*NS + l] = 0.5f*(vQw[l] + vQw[32 + l]);
        // yield activation
        float f = qreg;
        float ratio = fminf(fabsf(f) / s_sig[jl], 15.f);
        float rp = __powf(ratio, pexp);
        f = f / __powf(1.f + rp, pinv);
        if (l < DM) vx[l] = f;
        // proj1 (bf16) + ReLU
        float4 a4 = {0,0,0,0};
        #pragma unroll
        for (int d4 = 0; d4 < 12; ++d4) {
            uint2 rw = *(const uint2*)&s_p1[jl*PST + d4*4];
            float4 x4 = *(const float4*)&vx[d4*4];
            a4.x = fmaf(bu2f_lo(rw.x), x4.x, a4.x);
            a4.y = fmaf(bu2f_hi(rw.x), x4.y, a4.y);
            a4.z = fmaf(bu2f_lo(rw.y), x4.z, a4.z);
            a4.w = fmaf(bu2f_hi(rw.y), x4.w, a4.w);
        }
        float h1 = fmaxf(0.f, s_p1b[jl] + (a4.x + a4.y) + (a4.z + a4.w));
        if (l < DM) vx[l] = h1;
        // proj2 (bf16)
        float4 c4 = {0,0,0,0};
        #pragma unroll
        for (int d4 = 0; d4 < 12; ++d4) {
            uint2 rw = *(const uint2*)&s_p2[jl*PST + d4*4];
            float4 x4 = *(const float4*)&vx[d4*4];
            c4.x = fmaf(bu2f_lo(rw.x), x4.x, c4.x);
            c4.y = fmaf(bu2f_hi(rw.x), x4.y, c4.y);
            c4.z = fmaf(bu2f_lo(rw.y), x4.z, c4.z);
            c4.w = fmaf(bu2f_hi(rw.y), x4.w, c4.w);
        }
        if (l < DM) outp[(size_t)m*DM + l] = s_p2b[jl] + (c4.x + c4.y) + (c4.z + c4.w);
    }
}

extern "C" void kernel_launch(void* const* d_in, const int* in_sizes, int n_in,
                              void* d_out, int out_size, void* d_ws, size_t ws_size,
                              hipStream_t stream) {
    const float* slot = (const float*)d_in[0];
    const float* fq   = (const float*)d_in[1];
    const float* ipw  = (const float*)d_in[2];
    const float* ipb  = (const float*)d_in[3];
    const float* opw  = (const float*)d_in[4];
    const float* opb  = (const float*)d_in[5];
    const float* lnqg = (const float*)d_in[6];
    const float* lnqb = (const float*)d_in[7];
    const float* lnkg = (const float*)d_in[8];
    const float* lnkb = (const float*)d_in[9];
    const float* wih  = (const float*)d_in[10];
    const float* whh  = (const float*)d_in[11];
    const float* bihp = (const float*)d_in[12];
    const float* bhhp = (const float*)d_in[13];
    const float* sigr = (const float*)d_in[14];
    const float* praw = (const float*)d_in[15];
    const float* p1w  = (const float*)d_in[16];
    const float* p1b  = (const float*)d_in[17];
    const float* p2w  = (const float*)d_in[18];
    const float* p2b  = (const float*)d_in[19];
    const int M = in_sizes[0] / (NS*DM);   // 65536
    fusion_kernel<<<dim3(256), dim3(768), 0, stream>>>(
        slot, fq, ipw, ipb, opw, opb, lnqg, lnqb, lnkg, lnkb,
        wih, whh, bihp, bhhp, sigr, praw, p1w, p1b, p2w, p2b,
        (float*)d_out, M);
}